// Round 5
// baseline (9797.794 us; speedup 1.0000x reference)
//
#include <hip/hip_runtime.h>
#include <cstddef>

// ---------- types ----------
typedef _Float16 f16x8 __attribute__((ext_vector_type(8)));
typedef _Float16 f16x4 __attribute__((ext_vector_type(4)));
typedef short    s16x8 __attribute__((ext_vector_type(8)));
typedef short    s16x4 __attribute__((ext_vector_type(4)));
typedef float    f32x4 __attribute__((ext_vector_type(4)));

#define MFMA_F16(a, b, c) __builtin_amdgcn_mfma_f32_16x16x32_f16((a), (b), (c), 0, 0, 0)

constexpr int GB = 512, GT = 256, GF = 64;
constexpr int GH1 = 256, GH2 = 128, GH3 = 64;
constexpr int THREADS = 512;   // 8 waves per wg, every stage

#if __has_builtin(__builtin_amdgcn_rcpf)
__device__ __forceinline__ float fast_rcp(float x) { return __builtin_amdgcn_rcpf(x); }
#else
__device__ __forceinline__ float fast_rcp(float x) { return 1.f / x; }
#endif

__device__ __forceinline__ f16x8 ld8(const short* p) {
  return __builtin_bit_cast(f16x8, *(const s16x8*)p);
}
__device__ __forceinline__ f16x4 ld4(const short* p) {
  return __builtin_bit_cast(f16x4, *(const s16x4*)p);
}

// LDS-only barrier: global prefetches/stores stay in flight across it.
__device__ __forceinline__ void barrier_nodrain() {
  asm volatile("s_waitcnt lgkmcnt(0)" ::: "memory");
  __builtin_amdgcn_s_barrier();
  asm volatile("" ::: "memory");
}

// ---------- chunk flag protocol ----------
// gfx94x cache-op mapping: AGENT-relaxed load sets only sc0 -> served from the
// polling XCD's LOCAL L2, which is never invalidated => stale spin until random
// eviction (round-3's 600us/chunk stall). AGENT-acquire invalidates L2 per poll
// (round-2 thrash). Correct cheap poll: SYSTEM-relaxed load = sc0+sc1 ->
// bypasses L1 AND L2, reads the coherent MALL each time, no invalidation.
__device__ __forceinline__ void stage_wait(int* f, int target, int tid) {
  if (tid == 0) {
    while (__hip_atomic_load(f, __ATOMIC_RELAXED, __HIP_MEMORY_SCOPE_SYSTEM) < target)
      __builtin_amdgcn_s_sleep(16);
  }
  __syncthreads();
  __threadfence();  // one L2 invalidate per wake: ring-slot re-reads are fresh
}
// Publish: per-wave drain stores, join, then a SYSTEM-scope RELEASE store:
// the release at system scope writes back dirty L2 (ring/h lines -> MALL) and
// the store itself lands sc0+sc1 where the system-scope poll reads it.
__device__ __forceinline__ void stage_publish(int* f, int val, int tid) {
  asm volatile("s_waitcnt vmcnt(0)" ::: "memory");
  __syncthreads();
  if (tid == 0)
    __hip_atomic_store(f, val, __ATOMIC_RELEASE, __HIP_MEMORY_SCOPE_SYSTEM);
}

// ---------- fp32 -> fp16 casts + flag zeroing, one launch ----------
struct CastDesc { const float* src; short* dst; int n; };
struct CastArgs { CastDesc d[7]; int* flags; };

__global__ void cast_many(CastArgs a) {
  const int tid = blockIdx.x * blockDim.x + threadIdx.x;
  const int stride = gridDim.x * blockDim.x;
  if (blockIdx.x == 0 && threadIdx.x < 128)
    __hip_atomic_store(a.flags + threadIdx.x, 0, __ATOMIC_RELEASE,
                       __HIP_MEMORY_SCOPE_SYSTEM);
#pragma unroll
  for (int j = 0; j < 7; j++) {
    const float* __restrict__ s = a.d[j].src;
    short* __restrict__ o = a.d[j].dst;
    const int n = a.d[j].n;
    for (int i = tid; i < n; i += stride)
      o[i] = __builtin_bit_cast(short, (_Float16)s[i]);
  }
}

// ---------- gemm stage: A @ W^T + b -> ring (tile-major) ----------
// 8 waves, JT 16-col tiles per wave. Weights register-resident.
// Chunk-local A prefetch only (input chunk may not be published earlier).
template <int KK, int NO, int JT, bool HASIN>
__device__ __forceinline__ void g_run(const short* __restrict__ A,
                                      const short* __restrict__ W,
                                      const float* __restrict__ bias,
                                      short* __restrict__ ring,
                                      int* Fin, int* Fbp, int* Fout,
                                      int bt, int C, int NB, int tid) {
  constexpr int KC = KK / 32;
  const int lane = tid & 63, wid = tid >> 6;
  const int p = lane & 15, q = lane >> 4;
  const int j0 = wid * 16 * JT;

  f16x8 wb[JT][KC];
  float bc[JT];
#pragma unroll
  for (int jt = 0; jt < JT; jt++) {
    const int col = j0 + jt * 16 + p;
    bc[jt] = bias[col];
#pragma unroll
    for (int kc = 0; kc < KC; kc++)
      wb[jt][kc] = ld8(W + (size_t)col * KK + kc * 32 + q * 8);
  }
  const short* arow = A + (size_t)(bt * 16 + p) * GT * KK + q * 8;
  const int NC = GT / C;

  f16x8 ab0[KC], ab1[KC];

  auto body = [&](int t, short* slot, int ti, f16x8 (&ac)[KC], f16x8 (&an)[KC]) {
    if (ti + 1 < C) {  // prefetch next t within this chunk only
#pragma unroll
      for (int kc = 0; kc < KC; kc++)
        an[kc] = ld8(arow + (size_t)(t + 1) * KK + kc * 32);
    }
    f32x4 acc[JT];
#pragma unroll
    for (int jt = 0; jt < JT; jt++)
      acc[jt] = f32x4{bc[jt], bc[jt], bc[jt], bc[jt]};
#pragma unroll
    for (int kc = 0; kc < KC; kc++)
#pragma unroll
      for (int jt = 0; jt < JT; jt++)
        acc[jt] = MFMA_F16(ac[kc], wb[jt][kc], acc[jt]);
    short* ob = slot + (size_t)ti * NO * 16;
#pragma unroll
    for (int jt = 0; jt < JT; jt++) {  // C/D: col = lane&15, row = q*4+r
      const int col = j0 + jt * 16 + p;
      s16x4 v;
#pragma unroll
      for (int r = 0; r < 4; r++)
        v[r] = __builtin_bit_cast(short, (_Float16)acc[jt][r]);
      *(s16x4*)&ob[col * 16 + q * 4] = v;
    }
  };

  for (int c = 0; c < NC; ++c) {
    if (HASIN) stage_wait(Fin + bt, c + 1, tid);
    if (c >= NB) stage_wait(Fbp + bt, c + 1 - NB, tid);  // ring backpressure
    short* slot = ring + ((size_t)(c % NB) * 32 + bt) * ((size_t)C * NO * 16);
#pragma unroll
    for (int kc = 0; kc < KC; kc++)
      ab0[kc] = ld8(arow + (size_t)(c * C) * KK + kc * 32);
#pragma unroll 1
    for (int ti = 0; ti < C; ti += 2) {
      body(c * C + ti,     slot, ti,     ab0, ab1);
      body(c * C + ti + 1, slot, ti + 1, ab1, ab0);
    }
    stage_publish(Fout + bt, c + 1, tid);
  }
}

// ---------- rec stage: sequential GRU over T, chunked, flag-chained ----------
// XG=true : input gates precomputed in the xg ring (r1, r2).
// XG=false: inline input projection, Wih register-resident (r3).
// Whh r,z register-resident; n-gate: KREG k-frags in regs, rest in LDS.
// ACT: active waves (others just keep the barriers company).
template <int H, int HIN, int JT, int KREG, int ACT, bool SEQ, bool XG>
__device__ __forceinline__ void rec_run(const short* __restrict__ xin,
                                        const short* __restrict__ Wih,
                                        const short* __restrict__ Whh,
                                        const float* __restrict__ bih,
                                        const float* __restrict__ bhh,
                                        short* __restrict__ hout,
                                        float* __restrict__ hfin,
                                        int* Fin, int* Fout,
                                        int bt, int C, int NB, int tid, short* smem) {
  constexpr int KS = H / 32;
  constexpr int KSI = HIN / 32;
  constexpr int KLDS = KS - KREG;
  constexpr int HP = H + 8;
  constexpr int WNP = KLDS * 32 + 8;
  constexpr int NO = 3 * H;

  short* wn = smem;                                // [H][WNP] if KLDS>0
  short* hb = smem + (KLDS > 0 ? H * WNP : 0);     // [2][16][HP]

  const int lane = tid & 63, wid = tid >> 6;
  const int p = lane & 15, q = lane >> 4;
  const int b0 = bt * 16;
  const int j0 = wid * 16 * JT;
  const bool act = wid < ACT;

  if constexpr (KLDS > 0) {  // stage n-gate k-tail of Whh into LDS (once)
    constexpr int KV = KLDS * 4;
    for (int i = tid; i < H * KV; i += THREADS) {
      const int row = i / KV, kc = i - row * KV;
      *(s16x8*)&wn[row * WNP + kc * 8] =
          *(const s16x8*)&Whh[(size_t)(2 * H + row) * H + KREG * 32 + kc * 8];
    }
  }
  for (int i = tid; i < 2 * 16 * HP; i += THREADS) hb[i] = 0;

  // register-resident weights (round-1-proven shapes; act-guarded: cols OOB otherwise)
  f16x8 wrz[JT][2][KS];
  f16x8 wnr[JT][KREG > 0 ? KREG : 1];
  f16x8 wih[XG ? 1 : JT][3][XG ? 1 : KSI];
  float br[JT], bz[JT], bn_h[JT], bn_x[XG ? 1 : JT];
  int wrow[JT], loff[XG ? JT : 1][3];
  if (act) {
#pragma unroll
    for (int jt = 0; jt < JT; jt++) {
      const int col = j0 + jt * 16 + p;
#pragma unroll
      for (int g = 0; g < 2; g++)
#pragma unroll
        for (int k = 0; k < KS; k++)
          wrz[jt][g][k] = ld8(Whh + (size_t)(g * H + col) * H + k * 32 + q * 8);
#pragma unroll
      for (int k = 0; k < KREG; k++)
        wnr[jt][k] = ld8(Whh + (size_t)(2 * H + col) * H + k * 32 + q * 8);
      wrow[jt] = col;
      bn_h[jt] = bhh[2 * H + col];
      if constexpr (XG) {
        br[jt] = bhh[col];
        bz[jt] = bhh[H + col];
#pragma unroll
        for (int g = 0; g < 3; g++) loff[jt][g] = (g * H + col) * 16 + q * 4;
      } else {
        br[jt] = bih[col] + bhh[col];
        bz[jt] = bih[H + col] + bhh[H + col];
        bn_x[jt] = bih[2 * H + col];
#pragma unroll
        for (int g = 0; g < 3; g++)
#pragma unroll
          for (int k = 0; k < KSI; k++)
            wih[jt][g][k] = ld8(Wih + (size_t)(g * H + col) * HIN + k * 32 + q * 8);
      }
    }
  }

  float hprev[JT][4];
#pragma unroll
  for (int jt = 0; jt < JT; jt++)
#pragma unroll
    for (int r = 0; r < 4; r++) hprev[jt][r] = 0.f;

  const short* xrow = nullptr;
  if constexpr (!XG) xrow = xin + (size_t)(b0 + p) * GT * HIN + q * 8;

  f16x4 xb4[2][XG ? JT : 1][3];
  f16x8 xb8[2][XG ? 1 : KSI];

  __syncthreads();

  const int NC = GT / C;
  for (int c = 0; c < NC; ++c) {
    stage_wait(Fin + bt, c + 1, tid);
    const short* xchunk = nullptr;
    if constexpr (XG)
      xchunk = xin + ((size_t)(c % NB) * 32 + bt) * ((size_t)C * NO * 16);
    if (act) {  // prime 2 steps (latency hides under first recurrence k-loop)
#pragma unroll
      for (int u = 0; u < 2; u++) {
        if constexpr (XG) {
#pragma unroll
          for (int jt = 0; jt < JT; jt++)
#pragma unroll
            for (int g = 0; g < 3; g++)
              xb4[u][jt][g] = ld4(xchunk + (size_t)u * NO * 16 + loff[jt][g]);
        } else {
#pragma unroll
          for (int k = 0; k < KSI; k++)
            xb8[u][k] = ld8(xrow + (size_t)(c * C + u) * HIN + k * 32);
        }
      }
    }

#pragma unroll 1
    for (int s = 0; s < C; ++s) {
      const int t = c * C + s;
      const int u = s & 1;            // C even: every chunk starts at buffer 0
      short* hbc = hb + u * 16 * HP;
      short* hbn = hb + (u ^ 1) * 16 * HP;

      if (act) {
        f32x4 ar[JT], az[JT], an[JT], axn[XG ? 1 : JT];
#pragma unroll
        for (int jt = 0; jt < JT; jt++) {
          if constexpr (XG) {
#pragma unroll
            for (int r = 0; r < 4; r++) {
              ar[jt][r] = (float)xb4[u][jt][0][r];
              az[jt][r] = (float)xb4[u][jt][1][r];
            }
          } else {
            ar[jt] = f32x4{0.f, 0.f, 0.f, 0.f};
            az[jt] = f32x4{0.f, 0.f, 0.f, 0.f};
            axn[jt] = f32x4{0.f, 0.f, 0.f, 0.f};
          }
          an[jt] = f32x4{0.f, 0.f, 0.f, 0.f};
        }

        // recurrence: k outer, h fragment shared across jt
#pragma unroll
        for (int k = 0; k < KS; k++) {
          const f16x8 ahk = ld8(&hbc[p * HP + k * 32 + q * 8]);
#pragma unroll
          for (int jt = 0; jt < JT; jt++) {
            ar[jt] = MFMA_F16(ahk, wrz[jt][0][k], ar[jt]);
            az[jt] = MFMA_F16(ahk, wrz[jt][1][k], az[jt]);
            if (k < KREG) {
              an[jt] = MFMA_F16(ahk, wnr[jt][k < KREG ? k : 0], an[jt]);
            } else {
              const f16x8 wnk = ld8(&wn[wrow[jt] * WNP + (k - KREG) * 32 + q * 8]);
              an[jt] = MFMA_F16(ahk, wnk, an[jt]);
            }
          }
        }
        if constexpr (!XG) {  // inline input projection (registers only)
#pragma unroll
          for (int k = 0; k < KSI; k++)
#pragma unroll
            for (int jt = 0; jt < JT; jt++) {
              ar[jt]  = MFMA_F16(xb8[u][k], wih[jt][0][k], ar[jt]);
              az[jt]  = MFMA_F16(xb8[u][k], wih[jt][1][k], az[jt]);
              axn[jt] = MFMA_F16(xb8[u][k], wih[jt][2][k], axn[jt]);
            }
        }

        // epilogue: C/D layout col = lane&15, row = q*4+r
#pragma unroll
        for (int jt = 0; jt < JT; jt++) {
          const int col = j0 + jt * 16 + p;
#pragma unroll
          for (int r = 0; r < 4; r++) {
            const int bm = q * 4 + r;
            const float rpre = ar[jt][r] + br[jt];
            const float zpre = az[jt][r] + bz[jt];
            const float rg = fast_rcp(1.f + __expf(-rpre));
            const float zg = fast_rcp(1.f + __expf(-zpre));
            float xnv;
            if constexpr (XG) xnv = (float)xb4[u][jt][2][r];
            else              xnv = axn[jt][r] + bn_x[jt];
            const float narg = xnv + rg * (an[jt][r] + bn_h[jt]);
            const float e2 = __expf(2.f * narg);
            const float ng = 1.f - 2.f * fast_rcp(e2 + 1.f);  // tanh
            const float hnew = (1.f - zg) * ng + zg * hprev[jt][r];
            hprev[jt][r] = hnew;
            const _Float16 hf = (_Float16)hnew;
            hbn[bm * HP + col] = __builtin_bit_cast(short, hf);
            if constexpr (SEQ)
              hout[((size_t)(b0 + bm) * GT + t) * H + col] = __builtin_bit_cast(short, hf);
            else if (t == GT - 1)
              hfin[(size_t)(b0 + bm) * H + col] = hnew;
          }
        }
        // refill xb[u] for step s+2 (stay inside the flagged chunk)
        if (s + 2 < C) {
          if constexpr (XG) {
#pragma unroll
            for (int jt = 0; jt < JT; jt++)
#pragma unroll
              for (int g = 0; g < 3; g++)
                xb4[u][jt][g] = ld4(xchunk + (size_t)(s + 2) * NO * 16 + loff[jt][g]);
          } else {
#pragma unroll
            for (int k = 0; k < KSI; k++)
              xb8[u][k] = ld8(xrow + (size_t)(t + 2) * HIN + k * 32);
          }
        }
      }
      barrier_nodrain();
    }
    if (Fout) stage_publish(Fout + bt, c + 1, tid);
  }
}

// ---------- the persistent 5-stage pipeline ----------
struct PipeArgs {
  const short* xh;
  const short* wih1; const short* whh1; const float* bih1; const float* bhh1;
  const short* wih2; const short* whh2; const float* bih2; const float* bhh2;
  const short* wih3; const short* whh3; const float* bih3; const float* bhh3;
  short* xg1; short* xg2; short* h1; short* h2; float* hstate;
  int* F1; int* FR1; int* F2; int* FR2;
  int C, NB1, NB2;
};

__global__ __launch_bounds__(THREADS, 1)
void gru_pipe(PipeArgs a) {
  extern __shared__ __align__(16) short smem[];
  // same-XCD placement heuristic: all 5 stages of a bt share blockIdx % 8.
  const int x = blockIdx.x;
  const int xcd = x & 7, rest = x >> 3;
  const int stage = rest % 5, btg = rest / 5;
  const int bt = xcd + 8 * btg;
  const int tid = threadIdx.x;

  if (stage == 0) {        // g1: x @ Wih1
    g_run<GF, 3 * GH1, 6, false>(a.xh, a.wih1, a.bih1, a.xg1,
                                 nullptr, a.FR1, a.F1, bt, a.C, a.NB1, tid);
  } else if (stage == 1) { // r1: H=256 recurrence (round-1 geometry)
    rec_run<GH1, GF, 2, 0, 8, true, true>(a.xg1, nullptr, a.whh1, nullptr, a.bhh1,
                                          a.h1, nullptr, a.F1, a.FR1,
                                          bt, a.C, a.NB1, tid, smem);
  } else if (stage == 2) { // g2: h1 @ Wih2
    g_run<GH1, 3 * GH2, 3, true>(a.h1, a.wih2, a.bih2, a.xg2,
                                 a.FR1, a.FR2, a.F2, bt, a.C, a.NB2, tid);
  } else if (stage == 3) { // r2: H=128 recurrence, Whh fully in regs
    rec_run<GH2, GH1, 1, 4, 8, true, true>(a.xg2, nullptr, a.whh2, nullptr, a.bhh2,
                                           a.h2, nullptr, a.F2, a.FR2,
                                           bt, a.C, a.NB2, tid, smem);
  } else {                 // r3: H=64, inline projection, 4 active waves
    rec_run<GH3, GH2, 1, 2, 4, false, false>(a.h2, a.wih3, a.whh3, a.bih3, a.bhh3,
                                             nullptr, a.hstate, a.FR2, nullptr,
                                             bt, a.C, 1, tid, smem);
  }
}

// ---------- dense head ----------
__global__ void dense_kernel(const float* __restrict__ hl, const float* __restrict__ Wd,
                             const float* __restrict__ bd, float* __restrict__ out) {
  const int b = blockIdx.x * 64 + threadIdx.x;
  float a = bd[0];
#pragma unroll
  for (int k = 0; k < 64; k++) a = fmaf(hl[b * 64 + k], Wd[k], a);
  out[b] = a;
}

// ---------- host ----------
extern "C" void kernel_launch(void* const* d_in, const int* in_sizes, int n_in,
                              void* d_out, int out_size, void* d_ws, size_t ws_size,
                              hipStream_t stream) {
  constexpr int B = GB, T = GT, F = GF;
  constexpr int H1 = GH1, H2 = GH2, H3 = GH3;
  constexpr int M = B * T;

  const float* x     = (const float*)d_in[0];
  const float* W_ih1 = (const float*)d_in[1];
  const float* W_hh1 = (const float*)d_in[2];
  const float* b_ih1 = (const float*)d_in[3];
  const float* b_hh1 = (const float*)d_in[4];
  const float* W_ih2 = (const float*)d_in[5];
  const float* W_hh2 = (const float*)d_in[6];
  const float* b_ih2 = (const float*)d_in[7];
  const float* b_hh2 = (const float*)d_in[8];
  const float* W_ih3 = (const float*)d_in[9];
  const float* W_hh3 = (const float*)d_in[10];
  const float* b_ih3 = (const float*)d_in[11];
  const float* b_hh3 = (const float*)d_in[12];
  const float* W_d   = (const float*)d_in[13];
  const float* b_d   = (const float*)d_in[14];
  float* out = (float*)d_out;

  char* ws = (char*)d_ws;
  size_t off = 0;
  auto alloc = [&](size_t bytes) -> char* {
    char* pp = ws + off;
    off = (off + bytes + 255) & ~(size_t)255;
    return pp;
  };

  const int nx    = M * F;
  const int nwih1 = 3 * H1 * F,  nwhh1 = 3 * H1 * H1;
  const int nwih2 = 3 * H2 * H1, nwhh2 = 3 * H2 * H2;
  const int nwih3 = 3 * H3 * H2, nwhh3 = 3 * H3 * H3;

  short* xh     = (short*)alloc((size_t)nx * 2);
  short* wih1   = (short*)alloc((size_t)nwih1 * 2);
  short* whh1   = (short*)alloc((size_t)nwhh1 * 2);
  short* wih2   = (short*)alloc((size_t)nwih2 * 2);
  short* whh2   = (short*)alloc((size_t)nwhh2 * 2);
  short* wih3   = (short*)alloc((size_t)nwih3 * 2);
  short* whh3   = (short*)alloc((size_t)nwhh3 * 2);
  short* h1     = (short*)alloc((size_t)M * H1 * 2);
  short* h2     = (short*)alloc((size_t)M * H2 * 2);
  float* hstate = (float*)alloc((size_t)B * H3 * 4);
  int*   flags  = (int*)alloc(128 * sizeof(int));
  (void)n_in; (void)in_sizes; (void)out_size;

  // ring sizing: slot1 = 32bt * C * 768 * 16 * 2B, slot2 = 32 * C * 384 * 16 * 2B
  const size_t avail = (ws_size > off) ? (ws_size - off) : 0;
  const size_t perT1 = (size_t)32 * (3 * H1) * 16 * 2;  // 786432 B / timestep
  const size_t perT2 = (size_t)32 * (3 * H2) * 16 * 2;  // 393216 B / timestep
  int C = 16;
  while (C > 2 && 2 * (size_t)C * (perT1 + perT2) > avail) C >>= 1;
  int NB1 = 2, NB2 = 2;
  while (NB1 < 4 &&
         (size_t)(NB1 + 1) * C * perT1 + (size_t)NB2 * C * perT2 <= avail) NB1++;
  while (NB2 < 4 &&
         (size_t)NB1 * C * perT1 + (size_t)(NB2 + 1) * C * perT2 <= avail) NB2++;
  short* xg1 = (short*)(ws + off);
  short* xg2 = (short*)((char*)xg1 + (size_t)NB1 * C * perT1);

  CastArgs ca;
  ca.d[0] = {x, xh, nx};
  ca.d[1] = {W_ih1, wih1, nwih1};
  ca.d[2] = {W_hh1, whh1, nwhh1};
  ca.d[3] = {W_ih2, wih2, nwih2};
  ca.d[4] = {W_hh2, whh2, nwhh2};
  ca.d[5] = {W_ih3, wih3, nwih3};
  ca.d[6] = {W_hh3, whh3, nwhh3};
  ca.flags = flags;
  cast_many<<<1024, 256, 0, stream>>>(ca);

  // LDS: max over stages = r1: wn[256][264] + hb[2][16][264] = 152064 B
  constexpr int SMEM = 256 * 264 * 2 + 2 * 16 * (H1 + 8) * 2;
  (void)hipFuncSetAttribute((const void*)gru_pipe,
                            hipFuncAttributeMaxDynamicSharedMemorySize, SMEM);

  PipeArgs pa;
  pa.xh = xh;
  pa.wih1 = wih1; pa.whh1 = whh1; pa.bih1 = b_ih1; pa.bhh1 = b_hh1;
  pa.wih2 = wih2; pa.whh2 = whh2; pa.bih2 = b_ih2; pa.bhh2 = b_hh2;
  pa.wih3 = wih3; pa.whh3 = whh3; pa.bih3 = b_ih3; pa.bhh3 = b_hh3;
  pa.xg1 = xg1; pa.xg2 = xg2; pa.h1 = h1; pa.h2 = h2; pa.hstate = hstate;
  pa.F1 = flags; pa.FR1 = flags + 32; pa.F2 = flags + 64; pa.FR2 = flags + 96;
  pa.C = C; pa.NB1 = NB1; pa.NB2 = NB2;

  gru_pipe<<<160, THREADS, SMEM, stream>>>(pa);

  dense_kernel<<<B / 64, 64, 0, stream>>>(hstate, W_d, b_d, out);
}

// Round 6
// 3091.589 us; speedup vs baseline: 3.1692x; 3.1692x over previous
//
#include <hip/hip_runtime.h>
#include <cstddef>

// ---------- types ----------
typedef _Float16 f16x8 __attribute__((ext_vector_type(8)));
typedef _Float16 f16x4 __attribute__((ext_vector_type(4)));
typedef short    s16x8 __attribute__((ext_vector_type(8)));
typedef short    s16x4 __attribute__((ext_vector_type(4)));
typedef float    f32x4 __attribute__((ext_vector_type(4)));

#define MFMA_F16(a, b, c) __builtin_amdgcn_mfma_f32_16x16x32_f16((a), (b), (c), 0, 0, 0)

#if __has_builtin(__builtin_amdgcn_rcpf)
__device__ __forceinline__ float fast_rcp(float x) { return __builtin_amdgcn_rcpf(x); }
#else
__device__ __forceinline__ float fast_rcp(float x) { return 1.f / x; }
#endif

__device__ __forceinline__ f16x8 ld8(const short* p) {
  return __builtin_bit_cast(f16x8, *(const s16x8*)p);
}
__device__ __forceinline__ f16x4 ld4(const short* p) {
  return __builtin_bit_cast(f16x4, *(const s16x4*)p);
}

// Barrier WITHOUT the vmcnt(0) drain: LDS ordering only, so cross-step global
// prefetches and stores stay in flight.
__device__ __forceinline__ void barrier_nodrain() {
  asm volatile("s_waitcnt lgkmcnt(0)" ::: "memory");
  __builtin_amdgcn_s_barrier();
  asm volatile("" ::: "memory");
}

// ---------- fp32 -> fp16 casts, one launch ----------
struct CastDesc { const float* src; short* dst; int n; };
struct CastArgs { CastDesc d[7]; };

__global__ void cast_many(CastArgs a) {
  const int tid = blockIdx.x * blockDim.x + threadIdx.x;
  const int stride = gridDim.x * blockDim.x;
#pragma unroll
  for (int j = 0; j < 7; j++) {
    const float* __restrict__ s = a.d[j].src;
    short* __restrict__ o = a.d[j].dst;
    const int n = a.d[j].n;
    for (int i = tid; i < n; i += stride)
      o[i] = __builtin_bit_cast(short, (_Float16)s[i]);
  }
}

// ---------- input-projection GEMM (t-parallel, high occupancy) ----------
// xg[bt][t-t0][c][bm] = sum_k A[(bt*16+bm), t, k] * W[c][k] + bias[c], fp16.
template <int K, int NO, int NW, int JT>
__global__ __launch_bounds__(NW * 64, 2)
void xg_gemm(const short* __restrict__ A,    // [B, T, K] fp16
             const short* __restrict__ W,    // [NO, K] fp16
             const float* __restrict__ bias, // [NO] fp32 (b_ih)
             short* __restrict__ xg,         // [B/16][TC][NO][16] fp16
             int t0, int TC) {
  static_assert(NW * 16 * JT == NO, "wave tiling must cover NO");
  constexpr int T = 256;
  constexpr int TT = 16;     // timesteps per workgroup
  constexpr int KC = K / 32;
  const int lane = threadIdx.x & 63;
  const int wid  = threadIdx.x >> 6;
  const int p = lane & 15, q = lane >> 4;
  const int bt = blockIdx.x;
  const int tbeg = t0 + blockIdx.y * TT;
  const int j0 = wid * 16 * JT;

  f16x8 wb[JT][KC];
  float bc[JT];
#pragma unroll
  for (int jt = 0; jt < JT; jt++) {
    const int col = j0 + jt * 16 + p;
    bc[jt] = bias[col];
#pragma unroll
    for (int kc = 0; kc < KC; kc++)
      wb[jt][kc] = ld8(W + (size_t)col * K + kc * 32 + q * 8);
  }

  const short* arow = A + ((size_t)(bt * 16 + p) * T + tbeg) * K + q * 8;
  short* outb = xg + ((size_t)bt * TC + (tbeg - t0)) * NO * 16;

  f16x8 a0[KC], a1[KC];
#pragma unroll
  for (int kc = 0; kc < KC; kc++) a0[kc] = ld8(arow + kc * 32);

  auto step = [&](int ti, f16x8 (&ac)[KC], f16x8 (&anx)[KC], bool pf) {
    if (pf) {
#pragma unroll
      for (int kc = 0; kc < KC; kc++)
        anx[kc] = ld8(arow + (size_t)(ti + 1) * K + kc * 32);
    }
    f32x4 acc[JT];
#pragma unroll
    for (int jt = 0; jt < JT; jt++)
      acc[jt] = f32x4{bc[jt], bc[jt], bc[jt], bc[jt]};
#pragma unroll
    for (int kc = 0; kc < KC; kc++)
#pragma unroll
      for (int jt = 0; jt < JT; jt++)
        acc[jt] = MFMA_F16(ac[kc], wb[jt][kc], acc[jt]);
    short* ob = outb + (size_t)ti * NO * 16;
#pragma unroll
    for (int jt = 0; jt < JT; jt++) {  // C/D: col = lane&15, row = q*4+r
      const int col = j0 + jt * 16 + p;
      s16x4 v;
#pragma unroll
      for (int r = 0; r < 4; r++)
        v[r] = __builtin_bit_cast(short, (_Float16)acc[jt][r]);
      *(s16x4*)&ob[col * 16 + q * 4] = v;
    }
  };

#pragma unroll 1
  for (int ti = 0; ti < TT; ti += 2) {
    step(ti, a0, a1, true);
    step(ti + 1, a1, a0, ti + 2 < TT);
  }
}

// ---------- layer-1 recurrence (round-1-proven geometry) ----------
template <int H, int NW, int JT, bool NLDS, bool SEQ, int XD>
__global__ __launch_bounds__(NW * 64, (NW / 4 >= 2) ? 2 : 1)
void gru_rec(const short* __restrict__ xg,   // [B/16][TC][3H][16] fp16 (x·Wih^T + b_ih)
             const short* __restrict__ Whh,  // [3H, H] fp16
             const float* __restrict__ bhh,  // [3H]
             short* __restrict__ hseq,       // [B,T,H] fp16 if SEQ
             float* __restrict__ hstate,     // [B,H] fp32 chunk-carry
             int t0, int t1, int TC) {
  static_assert(NW * 16 * JT == H, "wave tiling must cover H");
  static_assert(XD == 2 || XD == 4, "XD even for static parity");
  constexpr int T = 256;
  constexpr int KS = H / 32;
  constexpr int HP = H + 8;
  constexpr int NO = 3 * H;

  extern __shared__ __align__(16) short smem[];
  short* wn = smem;                          // [H][HP] if NLDS
  short* hb = smem + (NLDS ? H * HP : 0);    // [2][16][HP]

  const int tid  = threadIdx.x;
  const int lane = tid & 63;
  const int wid  = tid >> 6;
  const int p = lane & 15, q = lane >> 4;
  const int b0 = blockIdx.x * 16;
  const int j0 = wid * 16 * JT;

  if constexpr (NLDS) {  // stage n-gate rows of Whh into LDS (one-time)
    constexpr int KV = H / 8;
    for (int i = tid; i < H * KV; i += NW * 64) {
      const int row = i / KV, kc = i - row * KV;
      *(s16x8*)&wn[row * HP + kc * 8] =
          *(const s16x8*)&Whh[(size_t)(2 * H + row) * H + kc * 8];
    }
  }
  if (t0 == 0) {
    for (int i = tid; i < 16 * HP; i += NW * 64) hb[i] = 0;
  } else {
    for (int i = tid; i < 16 * H; i += NW * 64) {
      const int row = i / H, col = i - row * H;
      hb[row * HP + col] =
          __builtin_bit_cast(short, (_Float16)hstate[(size_t)(b0 + row) * H + col]);
    }
  }

  f16x8 wr[JT][NLDS ? 2 : 3][KS];
#pragma unroll
  for (int jt = 0; jt < JT; jt++) {
    const int col = j0 + jt * 16 + p;
#pragma unroll
    for (int g = 0; g < (NLDS ? 2 : 3); g++)
#pragma unroll
      for (int k = 0; k < KS; k++)
        wr[jt][g][k] = ld8(Whh + (size_t)(g * H + col) * H + k * 32 + q * 8);
  }
  float bhr[JT], bhz[JT], bhn[JT];
  int wrow[JT];
#pragma unroll
  for (int jt = 0; jt < JT; jt++) {
    const int col = j0 + jt * 16 + p;
    wrow[jt] = col;
    bhr[jt] = bhh[col];
    bhz[jt] = bhh[H + col];
    bhn[jt] = bhh[2 * H + col];
  }

  float hprev[JT][4];
#pragma unroll
  for (int jt = 0; jt < JT; jt++)
#pragma unroll
    for (int r = 0; r < 4; r++)
      hprev[jt][r] = (t0 == 0) ? 0.f
                   : hstate[(size_t)(b0 + q * 4 + r) * H + (j0 + jt * 16 + p)];

  const size_t sbase = (size_t)blockIdx.x * TC * NO * 16;
  int loff[JT][3];
#pragma unroll
  for (int jt = 0; jt < JT; jt++)
#pragma unroll
    for (int g = 0; g < 3; g++)
      loff[jt][g] = (g * H + j0 + jt * 16 + p) * 16 + q * 4;

  f16x4 xb[XD][JT][3];
#pragma unroll
  for (int u = 0; u < XD; u++)
#pragma unroll
    for (int jt = 0; jt < JT; jt++)
#pragma unroll
      for (int g = 0; g < 3; g++)
        xb[u][jt][g] = ld4(xg + sbase + (size_t)u * NO * 16 + loff[jt][g]);

  __syncthreads();

  const int steps = t1 - t0;
#pragma unroll 1
  for (int sb = 0; sb < steps; sb += XD) {
#pragma unroll
    for (int u = 0; u < XD; u++) {
      const int s = sb + u;
      const int t = t0 + s;
      short* hbc = hb + (u & 1) * 16 * HP;
      short* hbn = hb + ((u & 1) ^ 1) * 16 * HP;

      f32x4 ar[JT], az[JT], an[JT];
#pragma unroll
      for (int jt = 0; jt < JT; jt++) {
#pragma unroll
        for (int r = 0; r < 4; r++) {
          ar[jt][r] = (float)xb[u][jt][0][r];
          az[jt][r] = (float)xb[u][jt][1][r];
        }
        an[jt] = f32x4{0.f, 0.f, 0.f, 0.f};
      }
#pragma unroll
      for (int k = 0; k < KS; k++) {
        const f16x8 ahk = ld8(&hbc[p * HP + k * 32 + q * 8]);
#pragma unroll
        for (int jt = 0; jt < JT; jt++) {
          ar[jt] = MFMA_F16(ahk, wr[jt][0][k], ar[jt]);
          az[jt] = MFMA_F16(ahk, wr[jt][1][k], az[jt]);
          if constexpr (NLDS) {
            const f16x8 wnk = ld8(&wn[wrow[jt] * HP + k * 32 + q * 8]);
            an[jt] = MFMA_F16(ahk, wnk, an[jt]);
          } else {
            an[jt] = MFMA_F16(ahk, wr[jt][2][k], an[jt]);
          }
        }
      }
#pragma unroll
      for (int jt = 0; jt < JT; jt++) {
        const int col = j0 + jt * 16 + p;
#pragma unroll
        for (int r = 0; r < 4; r++) {
          const int bm = q * 4 + r;
          const float rpre = ar[jt][r] + bhr[jt];
          const float zpre = az[jt][r] + bhz[jt];
          const float rg = fast_rcp(1.f + __expf(-rpre));
          const float zg = fast_rcp(1.f + __expf(-zpre));
          const float xnv = (float)xb[u][jt][2][r];
          const float narg = xnv + rg * (an[jt][r] + bhn[jt]);
          const float e2 = __expf(2.f * narg);
          const float ng = 1.f - 2.f * fast_rcp(e2 + 1.f);  // tanh
          const float hnew = (1.f - zg) * ng + zg * hprev[jt][r];
          hprev[jt][r] = hnew;
          const _Float16 hf = (_Float16)hnew;
          hbn[bm * HP + col] = __builtin_bit_cast(short, hf);
          if constexpr (SEQ)
            hseq[((size_t)(b0 + bm) * T + t) * H + col] = __builtin_bit_cast(short, hf);
        }
      }
      if (t == t1 - 1) {
#pragma unroll
        for (int jt = 0; jt < JT; jt++)
#pragma unroll
          for (int r = 0; r < 4; r++)
            hstate[(size_t)(b0 + q * 4 + r) * H + (j0 + jt * 16 + p)] = hprev[jt][r];
      }
      {  // refill xb[u] for step s+XD (chunk buffer has XD-row pad for overrun)
        const size_t s2 = sbase + (size_t)(s + XD) * NO * 16;
#pragma unroll
        for (int jt = 0; jt < JT; jt++)
#pragma unroll
          for (int g = 0; g < 3; g++)
            xb[u][jt][g] = ld4(xg + s2 + loff[jt][g]);
      }
      barrier_nodrain();
    }
  }
}

// ---------- fused layers 2+3 ----------
// One wg per 16 batch rows. Per step: all 8 waves compute h2(t) (Whh2 in regs,
// xg2 from the precomputed ring), ONE lgkm-barrier, then waves 0-3 compute
// h3(t) reading h2(t) directly from LDS (inline input projection, Wih3/Whh3 in
// regs). h2 never touches global; layer-3 gemm and separate r3 dispatch gone.
__global__ __launch_bounds__(512, 1)
void rec23(const short* __restrict__ xg2,   // [B/16][TC][384][16] fp16 (h1·Wih2^T + b_ih2)
           const short* __restrict__ Whh2,  // [384,128] fp16
           const float* __restrict__ bhh2,  // [384]
           const short* __restrict__ Wih3,  // [192,128] fp16
           const short* __restrict__ Whh3,  // [192,64] fp16
           const float* __restrict__ bih3,  // [192]
           const float* __restrict__ bhh3,  // [192]
           float* __restrict__ hs2,         // [B,128] fp32 chunk-carry
           float* __restrict__ hs3,         // [B,64] fp32 chunk-carry / final
           int t0, int t1, int TC) {
  constexpr int H2 = 128, H3 = 64;
  constexpr int HP2 = H2 + 8, HP3 = H3 + 8;
  constexpr int NO = 3 * H2;
  __shared__ __align__(16) short hb2[2][16][HP2];
  __shared__ __align__(16) short hb3[2][16][HP3];

  const int tid = threadIdx.x;
  const int lane = tid & 63, wid = tid >> 6;
  const int p = lane & 15, q = lane >> 4;
  const int bt = blockIdx.x, b0 = bt * 16;
  const int col2 = wid * 16 + p;            // 8 waves cover 128
  const int col3 = (wid & 3) * 16 + p;      // waves 0-3 cover 64
  const bool act3 = wid < 4;

  if (t0 == 0) {
    for (int i = tid; i < 2 * 16 * HP2; i += 512) (&hb2[0][0][0])[i] = 0;
    for (int i = tid; i < 2 * 16 * HP3; i += 512) (&hb3[0][0][0])[i] = 0;
  } else {
    for (int i = tid; i < 16 * H2; i += 512) {
      const int r = i / H2, c = i - r * H2;
      hb2[0][r][c] = __builtin_bit_cast(short, (_Float16)hs2[(size_t)(b0 + r) * H2 + c]);
    }
    for (int i = tid; i < 16 * H3; i += 512) {
      const int r = i / H3, c = i - r * H3;
      hb3[0][r][c] = __builtin_bit_cast(short, (_Float16)hs3[(size_t)(b0 + r) * H3 + c]);
    }
  }

  // layer-2 weights (regs/AGPR): 12 f16x8 per wave
  f16x8 w2[3][4];
#pragma unroll
  for (int g = 0; g < 3; g++)
#pragma unroll
    for (int k = 0; k < 4; k++)
      w2[g][k] = ld8(Whh2 + (size_t)(g * H2 + col2) * H2 + k * 32 + q * 8);
  const float br2 = bhh2[col2], bz2 = bhh2[H2 + col2], bn2 = bhh2[2 * H2 + col2];

  // layer-3 weights on waves 0-3: 18 f16x8
  f16x8 wi3[3][4], wh3[3][2];
  float br3 = 0.f, bz3 = 0.f, bn3x = 0.f, bn3h = 0.f;
  if (act3) {
#pragma unroll
    for (int g = 0; g < 3; g++) {
#pragma unroll
      for (int k = 0; k < 4; k++)
        wi3[g][k] = ld8(Wih3 + (size_t)(g * H3 + col3) * H2 + k * 32 + q * 8);
#pragma unroll
      for (int k = 0; k < 2; k++)
        wh3[g][k] = ld8(Whh3 + (size_t)(g * H3 + col3) * H3 + k * 32 + q * 8);
    }
    br3 = bih3[col3] + bhh3[col3];
    bz3 = bih3[H3 + col3] + bhh3[H3 + col3];
    bn3x = bih3[2 * H3 + col3];
    bn3h = bhh3[2 * H3 + col3];
  }

  float h2p[4], h3p[4];
#pragma unroll
  for (int r = 0; r < 4; r++) {
    h2p[r] = (t0 == 0) ? 0.f : hs2[(size_t)(b0 + q * 4 + r) * H2 + col2];
    h3p[r] = (!act3 || t0 == 0) ? 0.f : hs3[(size_t)(b0 + q * 4 + r) * H3 + col3];
  }

  const size_t sbase = (size_t)bt * TC * NO * 16;
  int loff[3];
#pragma unroll
  for (int g = 0; g < 3; g++) loff[g] = (g * H2 + col2) * 16 + q * 4;
  f16x4 xb[2][3];
#pragma unroll
  for (int u = 0; u < 2; u++)
#pragma unroll
    for (int g = 0; g < 3; g++)
      xb[u][g] = ld4(xg2 + sbase + (size_t)u * NO * 16 + loff[g]);

  __syncthreads();

  const int steps = t1 - t0;
#pragma unroll 1
  for (int s = 0; s < steps; ++s) {
    const int t = t0 + s;
    const int u = s & 1;
    // ---- layer 2 (all 8 waves) ----
    f32x4 ar, az, an;
#pragma unroll
    for (int r = 0; r < 4; r++) { ar[r] = (float)xb[u][0][r]; az[r] = (float)xb[u][1][r]; }
    an = f32x4{0.f, 0.f, 0.f, 0.f};
#pragma unroll
    for (int k = 0; k < 4; k++) {
      const f16x8 ahk = ld8(&hb2[u][p][k * 32 + q * 8]);
      ar = MFMA_F16(ahk, w2[0][k], ar);
      az = MFMA_F16(ahk, w2[1][k], az);
      an = MFMA_F16(ahk, w2[2][k], an);
    }
#pragma unroll
    for (int r = 0; r < 4; r++) {
      const int bm = q * 4 + r;
      const float rg = fast_rcp(1.f + __expf(-(ar[r] + br2)));
      const float zg = fast_rcp(1.f + __expf(-(az[r] + bz2)));
      const float narg = (float)xb[u][2][r] + rg * (an[r] + bn2);
      const float e2 = __expf(2.f * narg);
      const float ng = 1.f - 2.f * fast_rcp(e2 + 1.f);  // tanh
      const float hnew = (1.f - zg) * ng + zg * h2p[r];
      h2p[r] = hnew;
      hb2[u ^ 1][bm][col2] = __builtin_bit_cast(short, (_Float16)hnew);
      if (t == t1 - 1) hs2[(size_t)(b0 + bm) * H2 + col2] = hnew;
    }
    {  // refill xb[u] for step s+2 (pad rows allocated past the chunk)
      const size_t s2 = sbase + (size_t)(s + 2) * NO * 16;
#pragma unroll
      for (int g = 0; g < 3; g++) xb[u][g] = ld4(xg2 + s2 + loff[g]);
    }
    barrier_nodrain();  // h2(t) visible; xg refill + hs stores stay in flight
    // ---- layer 3 (waves 0-3); hazards separated by the per-step barrier ----
    if (act3) {
      f32x4 a3r{0.f,0.f,0.f,0.f}, a3z{0.f,0.f,0.f,0.f},
            a3x{0.f,0.f,0.f,0.f}, a3h{0.f,0.f,0.f,0.f};
#pragma unroll
      for (int k = 0; k < 4; k++) {           // input projection from h2(t) in LDS
        const f16x8 a2k = ld8(&hb2[u ^ 1][p][k * 32 + q * 8]);
        a3r = MFMA_F16(a2k, wi3[0][k], a3r);
        a3z = MFMA_F16(a2k, wi3[1][k], a3z);
        a3x = MFMA_F16(a2k, wi3[2][k], a3x);
      }
#pragma unroll
      for (int k = 0; k < 2; k++) {           // recurrence on h3(t-1)
        const f16x8 a3k = ld8(&hb3[u][p][k * 32 + q * 8]);
        a3r = MFMA_F16(a3k, wh3[0][k], a3r);
        a3z = MFMA_F16(a3k, wh3[1][k], a3z);
        a3h = MFMA_F16(a3k, wh3[2][k], a3h);
      }
#pragma unroll
      for (int r = 0; r < 4; r++) {
        const int bm = q * 4 + r;
        const float rg = fast_rcp(1.f + __expf(-(a3r[r] + br3)));
        const float zg = fast_rcp(1.f + __expf(-(a3z[r] + bz3)));
        const float narg = a3x[r] + bn3x + rg * (a3h[r] + bn3h);
        const float e2 = __expf(2.f * narg);
        const float ng = 1.f - 2.f * fast_rcp(e2 + 1.f);
        const float hnew = (1.f - zg) * ng + zg * h3p[r];
        h3p[r] = hnew;
        hb3[u ^ 1][bm][col3] = __builtin_bit_cast(short, (_Float16)hnew);
        if (t == t1 - 1) hs3[(size_t)(b0 + bm) * H3 + col3] = hnew;
      }
    }
  }
}

// ---------- dense head ----------
__global__ void dense_kernel(const float* __restrict__ hl, const float* __restrict__ Wd,
                             const float* __restrict__ bd, float* __restrict__ out) {
  const int b = blockIdx.x * 64 + threadIdx.x;
  float a = bd[0];
#pragma unroll
  for (int k = 0; k < 64; k++) a = fmaf(hl[b * 64 + k], Wd[k], a);
  out[b] = a;
}

// ---------- host ----------
extern "C" void kernel_launch(void* const* d_in, const int* in_sizes, int n_in,
                              void* d_out, int out_size, void* d_ws, size_t ws_size,
                              hipStream_t stream) {
  constexpr int B = 512, T = 256, F = 64;
  constexpr int H1 = 256, H2 = 128, H3 = 64;
  constexpr int M = B * T;

  const float* x     = (const float*)d_in[0];
  const float* W_ih1 = (const float*)d_in[1];
  const float* W_hh1 = (const float*)d_in[2];
  const float* b_ih1 = (const float*)d_in[3];
  const float* b_hh1 = (const float*)d_in[4];
  const float* W_ih2 = (const float*)d_in[5];
  const float* W_hh2 = (const float*)d_in[6];
  const float* b_ih2 = (const float*)d_in[7];
  const float* b_hh2 = (const float*)d_in[8];
  const float* W_ih3 = (const float*)d_in[9];
  const float* W_hh3 = (const float*)d_in[10];
  const float* b_ih3 = (const float*)d_in[11];
  const float* b_hh3 = (const float*)d_in[12];
  const float* W_d   = (const float*)d_in[13];
  const float* b_d   = (const float*)d_in[14];
  float* out = (float*)d_out;

  char* ws = (char*)d_ws;
  size_t off = 0;
  auto alloc = [&](size_t bytes) -> char* {
    char* pp = ws + off;
    off = (off + bytes + 255) & ~(size_t)255;
    return pp;
  };

  const int nx    = M * F;
  const int nwih1 = 3 * H1 * F,  nwhh1 = 3 * H1 * H1;
  const int nwih2 = 3 * H2 * H1, nwhh2 = 3 * H2 * H2;
  const int nwih3 = 3 * H3 * H2, nwhh3 = 3 * H3 * H3;

  short* xh   = (short*)alloc((size_t)nx * 2);
  short* wih1 = (short*)alloc((size_t)nwih1 * 2);
  short* whh1 = (short*)alloc((size_t)nwhh1 * 2);
  short* wih2 = (short*)alloc((size_t)nwih2 * 2);
  short* whh2 = (short*)alloc((size_t)nwhh2 * 2);
  short* wih3 = (short*)alloc((size_t)nwih3 * 2);
  short* whh3 = (short*)alloc((size_t)nwhh3 * 2);
  short* h1   = (short*)alloc((size_t)M * H1 * 2);
  float* hs1  = (float*)alloc((size_t)B * H1 * 4);
  float* hs2  = (float*)alloc((size_t)B * H2 * 4);
  float* hs3  = (float*)alloc((size_t)B * H3 * 4);
  short* xgbuf = (short*)(ws + off);
  const size_t avail = (ws_size > off) ? (ws_size - off) : 0;
  (void)n_in; (void)in_sizes; (void)out_size;

  CastArgs ca;
  ca.d[0] = {x, xh, nx};
  ca.d[1] = {W_ih1, wih1, nwih1};
  ca.d[2] = {W_hh1, whh1, nwhh1};
  ca.d[3] = {W_ih2, wih2, nwih2};
  ca.d[4] = {W_hh2, whh2, nwhh2};
  ca.d[5] = {W_ih3, wih3, nwih3};
  ca.d[6] = {W_hh3, whh3, nwhh3};
  cast_many<<<1024, 256, 0, stream>>>(ca);

  // largest chunk TC (pow2, >=16) whose xg buffer (+prefetch pad) fits
  auto pick_tc = [&](int NO, int XD) -> int {
    for (int tc = T; tc >= 32; tc >>= 1) {
      size_t need = (size_t)(B / 16) * tc * NO * 16 * 2
                  + (size_t)XD * NO * 16 * 2 + 256;
      if (need <= avail) return tc;
    }
    return 16;
  };

  constexpr int SM1 = (H1 + 2 * 16) * (H1 + 8) * 2;  // 152064 B
  auto* r1 = gru_rec<H1, 8, 2, true, true, 2>;
  (void)hipFuncSetAttribute((const void*)r1, hipFuncAttributeMaxDynamicSharedMemorySize, SM1);

  // ---- layer 1 ----
  {
    const int TC = pick_tc(3 * H1, 2);
    for (int t0 = 0; t0 < T; t0 += TC) {
      xg_gemm<F, 3 * H1, 4, 12><<<dim3(B / 16, TC / 16), 4 * 64, 0, stream>>>(
          xh, wih1, b_ih1, xgbuf, t0, TC);
      r1<<<B / 16, 8 * 64, SM1, stream>>>(xgbuf, whh1, b_hh1, h1, hs1, t0, t0 + TC, TC);
    }
  }
  // ---- layers 2+3 fused ----
  {
    const int TC = pick_tc(3 * H2, 2);
    for (int t0 = 0; t0 < T; t0 += TC) {
      xg_gemm<H1, 3 * H2, 8, 3><<<dim3(B / 16, TC / 16), 8 * 64, 0, stream>>>(
          h1, wih2, b_ih2, xgbuf, t0, TC);
      rec23<<<B / 16, 512, 0, stream>>>(xgbuf, whh2, b_hh2, wih3, whh3, b_ih3, b_hh3,
                                        hs2, hs3, t0, t0 + TC, TC);
    }
  }

  dense_kernel<<<B / 64, 64, 0, stream>>>(hs3, W_d, b_d, out);
}

// Round 7
// 946.919 us; speedup vs baseline: 10.3470x; 3.2649x over previous
//
#include <hip/hip_runtime.h>
#include <cstddef>

// ---------- types ----------
typedef _Float16 f16x8 __attribute__((ext_vector_type(8)));
typedef _Float16 f16x4 __attribute__((ext_vector_type(4)));
typedef short    s16x8 __attribute__((ext_vector_type(8)));
typedef short    s16x4 __attribute__((ext_vector_type(4)));
typedef float    f32x4 __attribute__((ext_vector_type(4)));

#define MFMA_F16(a, b, c) __builtin_amdgcn_mfma_f32_16x16x32_f16((a), (b), (c), 0, 0, 0)

#if __has_builtin(__builtin_amdgcn_rcpf)
__device__ __forceinline__ float fast_rcp(float x) { return __builtin_amdgcn_rcpf(x); }
#else
__device__ __forceinline__ float fast_rcp(float x) { return 1.f / x; }
#endif

__device__ __forceinline__ f16x8 ld8(const short* p) {
  return __builtin_bit_cast(f16x8, *(const s16x8*)p);
}
__device__ __forceinline__ f16x4 ld4(const short* p) {
  return __builtin_bit_cast(f16x4, *(const s16x4*)p);
}

// Barrier WITHOUT the vmcnt(0) drain: LDS ordering only, so cross-step global
// prefetches and stores stay in flight.
__device__ __forceinline__ void barrier_nodrain() {
  asm volatile("s_waitcnt lgkmcnt(0)" ::: "memory");
  __builtin_amdgcn_s_barrier();
  asm volatile("" ::: "memory");
}

// ---------- fp32 -> fp16 casts, one launch ----------
struct CastDesc { const float* src; short* dst; int n; };
struct CastArgs { CastDesc d[7]; };

__global__ void cast_many(CastArgs a) {
  const int tid = blockIdx.x * blockDim.x + threadIdx.x;
  const int stride = gridDim.x * blockDim.x;
#pragma unroll
  for (int j = 0; j < 7; j++) {
    const float* __restrict__ s = a.d[j].src;
    short* __restrict__ o = a.d[j].dst;
    const int n = a.d[j].n;
    for (int i = tid; i < n; i += stride)
      o[i] = __builtin_bit_cast(short, (_Float16)s[i]);
  }
}

// ---------- input-projection GEMM (t-parallel, high occupancy) ----------
// xg[bt][t-t0][c][bm] = sum_k A[(bt*16+bm), t, k] * W[c][k] + bias[c], fp16.
template <int K, int NO, int NW, int JT>
__global__ __launch_bounds__(NW * 64, 2)
void xg_gemm(const short* __restrict__ A,    // [B, T, K] fp16
             const short* __restrict__ W,    // [NO, K] fp16
             const float* __restrict__ bias, // [NO] fp32 (b_ih)
             short* __restrict__ xg,         // [B/16][TC][NO][16] fp16
             int t0, int TC) {
  static_assert(NW * 16 * JT == NO, "wave tiling must cover NO");
  constexpr int T = 256;
  constexpr int TT = 16;     // timesteps per workgroup
  constexpr int KC = K / 32;
  const int lane = threadIdx.x & 63;
  const int wid  = threadIdx.x >> 6;
  const int p = lane & 15, q = lane >> 4;
  const int bt = blockIdx.x;
  const int tbeg = t0 + blockIdx.y * TT;
  const int j0 = wid * 16 * JT;

  f16x8 wb[JT][KC];
  float bc[JT];
#pragma unroll
  for (int jt = 0; jt < JT; jt++) {
    const int col = j0 + jt * 16 + p;
    bc[jt] = bias[col];
#pragma unroll
    for (int kc = 0; kc < KC; kc++)
      wb[jt][kc] = ld8(W + (size_t)col * K + kc * 32 + q * 8);
  }

  const short* arow = A + ((size_t)(bt * 16 + p) * T + tbeg) * K + q * 8;
  short* outb = xg + ((size_t)bt * TC + (tbeg - t0)) * NO * 16;

  f16x8 a0[KC], a1[KC];
#pragma unroll
  for (int kc = 0; kc < KC; kc++) a0[kc] = ld8(arow + kc * 32);

  auto step = [&](int ti, f16x8 (&ac)[KC], f16x8 (&anx)[KC], bool pf) {
    if (pf) {
#pragma unroll
      for (int kc = 0; kc < KC; kc++)
        anx[kc] = ld8(arow + (size_t)(ti + 1) * K + kc * 32);
    }
    f32x4 acc[JT];
#pragma unroll
    for (int jt = 0; jt < JT; jt++)
      acc[jt] = f32x4{bc[jt], bc[jt], bc[jt], bc[jt]};
#pragma unroll
    for (int kc = 0; kc < KC; kc++)
#pragma unroll
      for (int jt = 0; jt < JT; jt++)
        acc[jt] = MFMA_F16(ac[kc], wb[jt][kc], acc[jt]);
    short* ob = outb + (size_t)ti * NO * 16;
#pragma unroll
    for (int jt = 0; jt < JT; jt++) {  // C/D: col = lane&15, row = q*4+r
      const int col = j0 + jt * 16 + p;
      s16x4 v;
#pragma unroll
      for (int r = 0; r < 4; r++)
        v[r] = __builtin_bit_cast(short, (_Float16)acc[jt][r]);
      *(s16x4*)&ob[col * 16 + q * 4] = v;
    }
  };

#pragma unroll 1
  for (int ti = 0; ti < TT; ti += 2) {
    step(ti, a0, a1, true);
    step(ti + 1, a1, a0, ti + 2 < TT);
  }
}

// ---------- layer-1 recurrence (round-1-proven geometry) ----------
template <int H, int NW, int JT, bool NLDS, bool SEQ, int XD>
__global__ __launch_bounds__(NW * 64, (NW / 4 >= 2) ? 2 : 1)
void gru_rec(const short* __restrict__ xg,   // [B/16][TC][3H][16] fp16 (x·Wih^T + b_ih)
             const short* __restrict__ Whh,  // [3H, H] fp16
             const float* __restrict__ bhh,  // [3H]
             short* __restrict__ hseq,       // [B,T,H] fp16 if SEQ
             float* __restrict__ hstate,     // [B,H] fp32 chunk-carry
             int t0, int t1, int TC) {
  static_assert(NW * 16 * JT == H, "wave tiling must cover H");
  static_assert(XD == 2 || XD == 4, "XD even for static parity");
  constexpr int T = 256;
  constexpr int KS = H / 32;
  constexpr int HP = H + 8;
  constexpr int NO = 3 * H;

  extern __shared__ __align__(16) short smem[];
  short* wn = smem;                          // [H][HP] if NLDS
  short* hb = smem + (NLDS ? H * HP : 0);    // [2][16][HP]

  const int tid  = threadIdx.x;
  const int lane = tid & 63;
  const int wid  = tid >> 6;
  const int p = lane & 15, q = lane >> 4;
  const int b0 = blockIdx.x * 16;
  const int j0 = wid * 16 * JT;

  if constexpr (NLDS) {  // stage n-gate rows of Whh into LDS (one-time)
    constexpr int KV = H / 8;
    for (int i = tid; i < H * KV; i += NW * 64) {
      const int row = i / KV, kc = i - row * KV;
      *(s16x8*)&wn[row * HP + kc * 8] =
          *(const s16x8*)&Whh[(size_t)(2 * H + row) * H + kc * 8];
    }
  }
  if (t0 == 0) {
    for (int i = tid; i < 16 * HP; i += NW * 64) hb[i] = 0;
  } else {
    for (int i = tid; i < 16 * H; i += NW * 64) {
      const int row = i / H, col = i - row * H;
      hb[row * HP + col] =
          __builtin_bit_cast(short, (_Float16)hstate[(size_t)(b0 + row) * H + col]);
    }
  }

  f16x8 wr[JT][NLDS ? 2 : 3][KS];
#pragma unroll
  for (int jt = 0; jt < JT; jt++) {
    const int col = j0 + jt * 16 + p;
#pragma unroll
    for (int g = 0; g < (NLDS ? 2 : 3); g++)
#pragma unroll
      for (int k = 0; k < KS; k++)
        wr[jt][g][k] = ld8(Whh + (size_t)(g * H + col) * H + k * 32 + q * 8);
  }
  float bhr[JT], bhz[JT], bhn[JT];
  int wrow[JT];
#pragma unroll
  for (int jt = 0; jt < JT; jt++) {
    const int col = j0 + jt * 16 + p;
    wrow[jt] = col;
    bhr[jt] = bhh[col];
    bhz[jt] = bhh[H + col];
    bhn[jt] = bhh[2 * H + col];
  }

  float hprev[JT][4];
#pragma unroll
  for (int jt = 0; jt < JT; jt++)
#pragma unroll
    for (int r = 0; r < 4; r++)
      hprev[jt][r] = (t0 == 0) ? 0.f
                   : hstate[(size_t)(b0 + q * 4 + r) * H + (j0 + jt * 16 + p)];

  const size_t sbase = (size_t)blockIdx.x * TC * NO * 16;
  int loff[JT][3];
#pragma unroll
  for (int jt = 0; jt < JT; jt++)
#pragma unroll
    for (int g = 0; g < 3; g++)
      loff[jt][g] = (g * H + j0 + jt * 16 + p) * 16 + q * 4;

  f16x4 xb[XD][JT][3];
#pragma unroll
  for (int u = 0; u < XD; u++)
#pragma unroll
    for (int jt = 0; jt < JT; jt++)
#pragma unroll
      for (int g = 0; g < 3; g++)
        xb[u][jt][g] = ld4(xg + sbase + (size_t)u * NO * 16 + loff[jt][g]);

  __syncthreads();

  const int steps = t1 - t0;
#pragma unroll 1
  for (int sb = 0; sb < steps; sb += XD) {
#pragma unroll
    for (int u = 0; u < XD; u++) {
      const int s = sb + u;
      const int t = t0 + s;
      short* hbc = hb + (u & 1) * 16 * HP;
      short* hbn = hb + ((u & 1) ^ 1) * 16 * HP;

      f32x4 ar[JT], az[JT], an[JT];
#pragma unroll
      for (int jt = 0; jt < JT; jt++) {
#pragma unroll
        for (int r = 0; r < 4; r++) {
          ar[jt][r] = (float)xb[u][jt][0][r];
          az[jt][r] = (float)xb[u][jt][1][r];
        }
        an[jt] = f32x4{0.f, 0.f, 0.f, 0.f};
      }
#pragma unroll
      for (int k = 0; k < KS; k++) {
        const f16x8 ahk = ld8(&hbc[p * HP + k * 32 + q * 8]);
#pragma unroll
        for (int jt = 0; jt < JT; jt++) {
          ar[jt] = MFMA_F16(ahk, wr[jt][0][k], ar[jt]);
          az[jt] = MFMA_F16(ahk, wr[jt][1][k], az[jt]);
          if constexpr (NLDS) {
            const f16x8 wnk = ld8(&wn[wrow[jt] * HP + k * 32 + q * 8]);
            an[jt] = MFMA_F16(ahk, wnk, an[jt]);
          } else {
            an[jt] = MFMA_F16(ahk, wr[jt][2][k], an[jt]);
          }
        }
      }
#pragma unroll
      for (int jt = 0; jt < JT; jt++) {
        const int col = j0 + jt * 16 + p;
#pragma unroll
        for (int r = 0; r < 4; r++) {
          const int bm = q * 4 + r;
          const float rpre = ar[jt][r] + bhr[jt];
          const float zpre = az[jt][r] + bhz[jt];
          const float rg = fast_rcp(1.f + __expf(-rpre));
          const float zg = fast_rcp(1.f + __expf(-zpre));
          const float xnv = (float)xb[u][jt][2][r];
          const float narg = xnv + rg * (an[jt][r] + bhn[jt]);
          const float e2 = __expf(2.f * narg);
          const float ng = 1.f - 2.f * fast_rcp(e2 + 1.f);  // tanh
          const float hnew = (1.f - zg) * ng + zg * hprev[jt][r];
          hprev[jt][r] = hnew;
          const _Float16 hf = (_Float16)hnew;
          hbn[bm * HP + col] = __builtin_bit_cast(short, hf);
          if constexpr (SEQ)
            hseq[((size_t)(b0 + bm) * T + t) * H + col] = __builtin_bit_cast(short, hf);
        }
      }
      if (t == t1 - 1) {
#pragma unroll
        for (int jt = 0; jt < JT; jt++)
#pragma unroll
          for (int r = 0; r < 4; r++)
            hstate[(size_t)(b0 + q * 4 + r) * H + (j0 + jt * 16 + p)] = hprev[jt][r];
      }
      {  // refill xb[u] for step s+XD (chunk buffer has XD-row pad for overrun)
        const size_t s2 = sbase + (size_t)(s + XD) * NO * 16;
#pragma unroll
        for (int jt = 0; jt < JT; jt++)
#pragma unroll
          for (int g = 0; g < 3; g++)
            xb[u][jt][g] = ld4(xg + s2 + loff[jt][g]);
      }
      barrier_nodrain();
    }
  }
}

// ---------- fused layers 2+3 ----------
// One wg per 16 batch rows. Per step: all 8 waves compute h2(t) (Whh2 in regs,
// xg2 from the precomputed ring), ONE lgkm-barrier, then waves 0-3 compute
// h3(t) reading h2(t) directly from LDS. h2 never touches global.
// CRITICAL (rule #20 fix vs round 6): the step loop is processed 2 steps per
// iteration with a fully-unrolled inner u-loop, so xb[u] / hb[u] indices are
// COMPILE-TIME. Round 6's runtime `u = s&1` sent xb to scratch: every step did
// global->reg->scratch->reg with an implicit vmcnt(0), 9.4us/step.
__global__ __launch_bounds__(512, 1)
void rec23(const short* __restrict__ xg2,   // [B/16][TC][384][16] fp16 (h1·Wih2^T + b_ih2)
           const short* __restrict__ Whh2,  // [384,128] fp16
           const float* __restrict__ bhh2,  // [384]
           const short* __restrict__ Wih3,  // [192,128] fp16
           const short* __restrict__ Whh3,  // [192,64] fp16
           const float* __restrict__ bih3,  // [192]
           const float* __restrict__ bhh3,  // [192]
           float* __restrict__ hs2,         // [B,128] fp32 chunk-carry
           float* __restrict__ hs3,         // [B,64] fp32 chunk-carry / final
           int t0, int t1, int TC) {
  constexpr int H2 = 128, H3 = 64;
  constexpr int HP2 = H2 + 8, HP3 = H3 + 8;
  constexpr int NO = 3 * H2;
  __shared__ __align__(16) short hb2[2][16][HP2];
  __shared__ __align__(16) short hb3[2][16][HP3];

  const int tid = threadIdx.x;
  const int lane = tid & 63, wid = tid >> 6;
  const int p = lane & 15, q = lane >> 4;
  const int bt = blockIdx.x, b0 = bt * 16;
  const int col2 = wid * 16 + p;            // 8 waves cover 128
  const int col3 = (wid & 3) * 16 + p;      // waves 0-3 cover 64
  const bool act3 = wid < 4;

  if (t0 == 0) {
    for (int i = tid; i < 2 * 16 * HP2; i += 512) (&hb2[0][0][0])[i] = 0;
    for (int i = tid; i < 2 * 16 * HP3; i += 512) (&hb3[0][0][0])[i] = 0;
  } else {
    for (int i = tid; i < 16 * H2; i += 512) {
      const int r = i / H2, c = i - r * H2;
      hb2[0][r][c] = __builtin_bit_cast(short, (_Float16)hs2[(size_t)(b0 + r) * H2 + c]);
    }
    for (int i = tid; i < 16 * H3; i += 512) {
      const int r = i / H3, c = i - r * H3;
      hb3[0][r][c] = __builtin_bit_cast(short, (_Float16)hs3[(size_t)(b0 + r) * H3 + c]);
    }
  }

  // layer-2 weights (regs): 12 f16x8 per wave
  f16x8 w2[3][4];
#pragma unroll
  for (int g = 0; g < 3; g++)
#pragma unroll
    for (int k = 0; k < 4; k++)
      w2[g][k] = ld8(Whh2 + (size_t)(g * H2 + col2) * H2 + k * 32 + q * 8);
  const float br2 = bhh2[col2], bz2 = bhh2[H2 + col2], bn2 = bhh2[2 * H2 + col2];

  // layer-3 weights on waves 0-3: 18 f16x8
  f16x8 wi3[3][4], wh3[3][2];
  float br3 = 0.f, bz3 = 0.f, bn3x = 0.f, bn3h = 0.f;
  if (act3) {
#pragma unroll
    for (int g = 0; g < 3; g++) {
#pragma unroll
      for (int k = 0; k < 4; k++)
        wi3[g][k] = ld8(Wih3 + (size_t)(g * H3 + col3) * H2 + k * 32 + q * 8);
#pragma unroll
      for (int k = 0; k < 2; k++)
        wh3[g][k] = ld8(Whh3 + (size_t)(g * H3 + col3) * H3 + k * 32 + q * 8);
    }
    br3 = bih3[col3] + bhh3[col3];
    bz3 = bih3[H3 + col3] + bhh3[H3 + col3];
    bn3x = bih3[2 * H3 + col3];
    bn3h = bhh3[2 * H3 + col3];
  }

  float h2p[4], h3p[4];
#pragma unroll
  for (int r = 0; r < 4; r++) {
    h2p[r] = (t0 == 0) ? 0.f : hs2[(size_t)(b0 + q * 4 + r) * H2 + col2];
    h3p[r] = (!act3 || t0 == 0) ? 0.f : hs3[(size_t)(b0 + q * 4 + r) * H3 + col3];
  }

  const size_t sbase = (size_t)bt * TC * NO * 16;
  int loff[3];
#pragma unroll
  for (int g = 0; g < 3; g++) loff[g] = (g * H2 + col2) * 16 + q * 4;
  f16x4 xb[2][3];
#pragma unroll
  for (int u = 0; u < 2; u++)
#pragma unroll
    for (int g = 0; g < 3; g++)
      xb[u][g] = ld4(xg2 + sbase + (size_t)u * NO * 16 + loff[g]);

  __syncthreads();

  const int steps = t1 - t0;
#pragma unroll 1
  for (int sb = 0; sb < steps; sb += 2) {
#pragma unroll
    for (int u = 0; u < 2; ++u) {   // fully unrolled: u is compile-time
      const int s = sb + u;
      const int t = t0 + s;
      // ---- layer 2 (all 8 waves) ----
      f32x4 ar, az, an;
#pragma unroll
      for (int r = 0; r < 4; r++) { ar[r] = (float)xb[u][0][r]; az[r] = (float)xb[u][1][r]; }
      an = f32x4{0.f, 0.f, 0.f, 0.f};
#pragma unroll
      for (int k = 0; k < 4; k++) {
        const f16x8 ahk = ld8(&hb2[u][p][k * 32 + q * 8]);
        ar = MFMA_F16(ahk, w2[0][k], ar);
        az = MFMA_F16(ahk, w2[1][k], az);
        an = MFMA_F16(ahk, w2[2][k], an);
      }
#pragma unroll
      for (int r = 0; r < 4; r++) {
        const int bm = q * 4 + r;
        const float rg = fast_rcp(1.f + __expf(-(ar[r] + br2)));
        const float zg = fast_rcp(1.f + __expf(-(az[r] + bz2)));
        const float narg = (float)xb[u][2][r] + rg * (an[r] + bn2);
        const float e2 = __expf(2.f * narg);
        const float ng = 1.f - 2.f * fast_rcp(e2 + 1.f);  // tanh
        const float hnew = (1.f - zg) * ng + zg * h2p[r];
        h2p[r] = hnew;
        hb2[u ^ 1][bm][col2] = __builtin_bit_cast(short, (_Float16)hnew);
        if (t == t1 - 1) hs2[(size_t)(b0 + bm) * H2 + col2] = hnew;
      }
      {  // refill xb[u] for step s+2 (pad rows allocated past the chunk)
        const size_t s2 = sbase + (size_t)(s + 2) * NO * 16;
#pragma unroll
        for (int g = 0; g < 3; g++) xb[u][g] = ld4(xg2 + s2 + loff[g]);
      }
      barrier_nodrain();  // h2(t) visible; xg refill + hs stores stay in flight
      // ---- layer 3 (waves 0-3); hazards separated by the per-step barrier ----
      if (act3) {
        f32x4 a3r{0.f,0.f,0.f,0.f}, a3z{0.f,0.f,0.f,0.f},
              a3x{0.f,0.f,0.f,0.f}, a3h{0.f,0.f,0.f,0.f};
#pragma unroll
        for (int k = 0; k < 4; k++) {           // input projection from h2(t) in LDS
          const f16x8 a2k = ld8(&hb2[u ^ 1][p][k * 32 + q * 8]);
          a3r = MFMA_F16(a2k, wi3[0][k], a3r);
          a3z = MFMA_F16(a2k, wi3[1][k], a3z);
          a3x = MFMA_F16(a2k, wi3[2][k], a3x);
        }
#pragma unroll
        for (int k = 0; k < 2; k++) {           // recurrence on h3(t-1)
          const f16x8 a3k = ld8(&hb3[u][p][k * 32 + q * 8]);
          a3r = MFMA_F16(a3k, wh3[0][k], a3r);
          a3z = MFMA_F16(a3k, wh3[1][k], a3z);
          a3h = MFMA_F16(a3k, wh3[2][k], a3h);
        }
#pragma unroll
        for (int r = 0; r < 4; r++) {
          const int bm = q * 4 + r;
          const float rg = fast_rcp(1.f + __expf(-(a3r[r] + br3)));
          const float zg = fast_rcp(1.f + __expf(-(a3z[r] + bz3)));
          const float narg = a3x[r] + bn3x + rg * (a3h[r] + bn3h);
          const float e2 = __expf(2.f * narg);
          const float ng = 1.f - 2.f * fast_rcp(e2 + 1.f);
          const float hnew = (1.f - zg) * ng + zg * h3p[r];
          h3p[r] = hnew;
          hb3[u ^ 1][bm][col3] = __builtin_bit_cast(short, (_Float16)hnew);
          if (t == t1 - 1) hs3[(size_t)(b0 + bm) * H3 + col3] = hnew;
        }
      }
    }
  }
}

// ---------- dense head ----------
__global__ void dense_kernel(const float* __restrict__ hl, const float* __restrict__ Wd,
                             const float* __restrict__ bd, float* __restrict__ out) {
  const int b = blockIdx.x * 64 + threadIdx.x;
  float a = bd[0];
#pragma unroll
  for (int k = 0; k < 64; k++) a = fmaf(hl[b * 64 + k], Wd[k], a);
  out[b] = a;
}

// ---------- host ----------
extern "C" void kernel_launch(void* const* d_in, const int* in_sizes, int n_in,
                              void* d_out, int out_size, void* d_ws, size_t ws_size,
                              hipStream_t stream) {
  constexpr int B = 512, T = 256, F = 64;
  constexpr int H1 = 256, H2 = 128, H3 = 64;
  constexpr int M = B * T;

  const float* x     = (const float*)d_in[0];
  const float* W_ih1 = (const float*)d_in[1];
  const float* W_hh1 = (const float*)d_in[2];
  const float* b_ih1 = (const float*)d_in[3];
  const float* b_hh1 = (const float*)d_in[4];
  const float* W_ih2 = (const float*)d_in[5];
  const float* W_hh2 = (const float*)d_in[6];
  const float* b_ih2 = (const float*)d_in[7];
  const float* b_hh2 = (const float*)d_in[8];
  const float* W_ih3 = (const float*)d_in[9];
  const float* W_hh3 = (const float*)d_in[10];
  const float* b_ih3 = (const float*)d_in[11];
  const float* b_hh3 = (const float*)d_in[12];
  const float* W_d   = (const float*)d_in[13];
  const float* b_d   = (const float*)d_in[14];
  float* out = (float*)d_out;

  char* ws = (char*)d_ws;
  size_t off = 0;
  auto alloc = [&](size_t bytes) -> char* {
    char* pp = ws + off;
    off = (off + bytes + 255) & ~(size_t)255;
    return pp;
  };

  const int nx    = M * F;
  const int nwih1 = 3 * H1 * F,  nwhh1 = 3 * H1 * H1;
  const int nwih2 = 3 * H2 * H1, nwhh2 = 3 * H2 * H2;
  const int nwih3 = 3 * H3 * H2, nwhh3 = 3 * H3 * H3;

  short* xh   = (short*)alloc((size_t)nx * 2);
  short* wih1 = (short*)alloc((size_t)nwih1 * 2);
  short* whh1 = (short*)alloc((size_t)nwhh1 * 2);
  short* wih2 = (short*)alloc((size_t)nwih2 * 2);
  short* whh2 = (short*)alloc((size_t)nwhh2 * 2);
  short* wih3 = (short*)alloc((size_t)nwih3 * 2);
  short* whh3 = (short*)alloc((size_t)nwhh3 * 2);
  short* h1   = (short*)alloc((size_t)M * H1 * 2);
  float* hs1  = (float*)alloc((size_t)B * H1 * 4);
  float* hs2  = (float*)alloc((size_t)B * H2 * 4);
  float* hs3  = (float*)alloc((size_t)B * H3 * 4);
  short* xgbuf = (short*)(ws + off);
  const size_t avail = (ws_size > off) ? (ws_size - off) : 0;
  (void)n_in; (void)in_sizes; (void)out_size;

  CastArgs ca;
  ca.d[0] = {x, xh, nx};
  ca.d[1] = {W_ih1, wih1, nwih1};
  ca.d[2] = {W_hh1, whh1, nwhh1};
  ca.d[3] = {W_ih2, wih2, nwih2};
  ca.d[4] = {W_hh2, whh2, nwhh2};
  ca.d[5] = {W_ih3, wih3, nwih3};
  ca.d[6] = {W_hh3, whh3, nwhh3};
  cast_many<<<1024, 256, 0, stream>>>(ca);

  // largest chunk TC (pow2, >=16) whose xg buffer (+prefetch pad) fits
  auto pick_tc = [&](int NO, int XD) -> int {
    for (int tc = T; tc >= 32; tc >>= 1) {
      size_t need = (size_t)(B / 16) * tc * NO * 16 * 2
                  + (size_t)XD * NO * 16 * 2 + 256;
      if (need <= avail) return tc;
    }
    return 16;
  };

  constexpr int SM1 = (H1 + 2 * 16) * (H1 + 8) * 2;  // 152064 B
  auto* r1 = gru_rec<H1, 8, 2, true, true, 2>;
  (void)hipFuncSetAttribute((const void*)r1, hipFuncAttributeMaxDynamicSharedMemorySize, SM1);

  // ---- layer 1 ----
  {
    const int TC = pick_tc(3 * H1, 2);
    for (int t0 = 0; t0 < T; t0 += TC) {
      xg_gemm<F, 3 * H1, 4, 12><<<dim3(B / 16, TC / 16), 4 * 64, 0, stream>>>(
          xh, wih1, b_ih1, xgbuf, t0, TC);
      r1<<<B / 16, 8 * 64, SM1, stream>>>(xgbuf, whh1, b_hh1, h1, hs1, t0, t0 + TC, TC);
    }
  }
  // ---- layers 2+3 fused ----
  {
    const int TC = pick_tc(3 * H2, 2);
    for (int t0 = 0; t0 < T; t0 += TC) {
      xg_gemm<H1, 3 * H2, 8, 3><<<dim3(B / 16, TC / 16), 8 * 64, 0, stream>>>(
          h1, wih2, b_ih2, xgbuf, t0, TC);
      rec23<<<B / 16, 512, 0, stream>>>(xgbuf, whh2, b_hh2, wih3, whh3, b_ih3, b_hh3,
                                        hs2, hs3, t0, t0 + TC, TC);
    }
  }

  dense_kernel<<<B / 64, 64, 0, stream>>>(hs3, W_d, b_d, out);
}